// Round 1
// baseline (477.233 us; speedup 1.0000x reference)
//
#include <hip/hip_runtime.h>

#define NVOX 150000
#define MTILES 586          // ceil(150000/256)
#define SROW 150016         // 586*256, column stride of h buffer
#define NCOL 320

typedef __attribute__((ext_vector_type(8))) short bf16x8;
typedef __attribute__((ext_vector_type(4))) float f32x4;

__device__ __forceinline__ unsigned short f2bf(float f) {
    unsigned u = __builtin_bit_cast(unsigned, f);
    u += 0x7fffu + ((u >> 16) & 1u);
    return (unsigned short)(u >> 16);
}

// ---------------- prep: features f32 -> bf16 (+ zero row at NVOX) ----------------
__global__ void prep_feat(const float* __restrict__ src, unsigned short* __restrict__ dst) {
    int i = blockIdx.x * 256 + threadIdx.x;
    if (i < NVOX * 64) dst[i] = f2bf(src[i]);
    else if (i < NVOX * 64 + 64) dst[i] = 0;  // zero row for invalid/pad gathers
}

// ---------------- prep: W3[h][kk][c][o] f32 -> Bt[h][o][k=kk*64+c] bf16; zero stats ----
__global__ void prep_w3(const float* __restrict__ w3, unsigned short* __restrict__ bt,
                        float* __restrict__ stats) {
    int i = blockIdx.x * 256 + threadIdx.x;   // grid is exactly 184320 threads
    int h = i / 36864;
    int rem = i - h * 36864;
    int kk = rem >> 12;
    int c = (rem >> 6) & 63;
    int o = rem & 63;
    bt[(size_t)(h * 64 + o) * 576 + kk * 64 + c] = f2bf(w3[i]);
    if (i < 2 * NCOL) stats[i] = 0.f;
}

// ---------------- gather-GEMM: h[col][row] = A(gathered) @ W3, bf16 MFMA ----------------
// BM=256, BN=64 (one head), BK=64 (one neighbor offset), 4 waves, wave tile 64x64.
__global__ __launch_bounds__(256, 3)
void gemm_kernel(const unsigned short* __restrict__ featB,
                 const unsigned short* __restrict__ Bt,
                 const int* __restrict__ nbr,
                 unsigned short* __restrict__ hbuf,
                 float* __restrict__ stats) {
    __shared__ __align__(16) unsigned short sA[256 * 72];  // +8 ushort pad per row
    __shared__ __align__(16) unsigned short sB[64 * 72];
    __shared__ float sRed[4 * 4 * 16 * 2];

    // XCD swizzle: 5 sibling N-tiles of one M-tile land on the same XCD (bid%8)
    int bid = blockIdx.x;
    int r = bid & 7, q_ = bid >> 3;
    int ntile = q_ % 5;
    int mtile = (q_ / 5) * 8 + r;
    if (mtile >= MTILES) return;
    int m0 = mtile * 256;
    int n0 = ntile * 64;

    int tid = threadIdx.x;
    int wave = tid >> 6, lane = tid & 63;
    int quad = lane >> 4, m16 = lane & 15;

    f32x4 acc[4][4];
#pragma unroll
    for (int mt = 0; mt < 4; ++mt)
#pragma unroll
        for (int nt = 0; nt < 4; ++nt)
            acc[mt][nt] = (f32x4){0.f, 0.f, 0.f, 0.f};

    int n_g = m0 + tid;
    bool rowvalid = (n_g < NVOX);
    const int* nbr_row = nbr + (size_t)(rowvalid ? n_g : 0) * 9;
    const unsigned short* btbase = Bt + (size_t)n0 * 576;  // this head's B rows

    for (int kk = 0; kk < 9; ++kk) {
        // ---- load phase (regs only) ----
        int idx = rowvalid ? nbr_row[kk] : -1;
        int srow = (idx < 0) ? NVOX : idx;
        const uint4* asrc = (const uint4*)(featB + (size_t)srow * 64);
        uint4 av[8];
#pragma unroll
        for (int j = 0; j < 8; ++j) av[j] = asrc[j];
        uint4 bv[2];
#pragma unroll
        for (int i = 0; i < 2; ++i) {
            int tk = tid + i * 256;
            int brow = tk >> 3, bc = tk & 7;
            bv[i] = *(const uint4*)(btbase + (size_t)brow * 576 + kk * 64 + bc * 8);
        }
        __syncthreads();   // previous compute done before overwriting LDS
        // ---- stage to LDS ----
        {
            unsigned short* dst = sA + tid * 72;
#pragma unroll
            for (int j = 0; j < 8; ++j) *(uint4*)(dst + j * 8) = av[j];
        }
#pragma unroll
        for (int i = 0; i < 2; ++i) {
            int tk = tid + i * 256;
            int brow = tk >> 3, bc = tk & 7;
            *(uint4*)(sB + brow * 72 + bc * 8) = bv[i];
        }
        __syncthreads();
        // ---- compute: 2 k-steps of 32, 16 MFMAs each ----
#pragma unroll
        for (int ks = 0; ks < 2; ++ks) {
            bf16x8 af[4], bf[4];
#pragma unroll
            for (int mt = 0; mt < 4; ++mt)
                af[mt] = *(const bf16x8*)(sA + (wave * 64 + mt * 16 + m16) * 72 + ks * 32 + quad * 8);
#pragma unroll
            for (int nt = 0; nt < 4; ++nt)
                bf[nt] = *(const bf16x8*)(sB + (nt * 16 + m16) * 72 + ks * 32 + quad * 8);
#pragma unroll
            for (int mt = 0; mt < 4; ++mt)
#pragma unroll
                for (int nt = 0; nt < 4; ++nt)
                    acc[mt][nt] = __builtin_amdgcn_mfma_f32_16x16x32_bf16(af[mt], bf[nt], acc[mt][nt], 0, 0, 0);
        }
    }

    // ---- epilogue: store h (bf16, column-major [col][row]) ----
#pragma unroll
    for (int mt = 0; mt < 4; ++mt) {
        int row0 = m0 + wave * 64 + mt * 16 + quad * 4;
#pragma unroll
        for (int nt = 0; nt < 4; ++nt) {
            int col = n0 + nt * 16 + m16;
            f32x4 v = acc[mt][nt];
            unsigned lo = (unsigned)f2bf(v.x) | ((unsigned)f2bf(v.y) << 16);
            unsigned hi = (unsigned)f2bf(v.z) | ((unsigned)f2bf(v.w) << 16);
            uint2 pk; pk.x = lo; pk.y = hi;
            *(uint2*)(hbuf + (size_t)col * SROW + row0) = pk;
        }
    }

    // ---- epilogue: BN statistics (pad rows are exactly zero -> no guard) ----
    float s[4], ss[4];
#pragma unroll
    for (int nt = 0; nt < 4; ++nt) {
        float a = 0.f, b = 0.f;
#pragma unroll
        for (int mt = 0; mt < 4; ++mt) {
            f32x4 v = acc[mt][nt];
            a += v.x + v.y + v.z + v.w;
            b += v.x * v.x + v.y * v.y + v.z * v.z + v.w * v.w;
        }
        s[nt] = a; ss[nt] = b;
    }
#pragma unroll
    for (int nt = 0; nt < 4; ++nt) {
        s[nt] += __shfl_xor(s[nt], 16); s[nt] += __shfl_xor(s[nt], 32);
        ss[nt] += __shfl_xor(ss[nt], 16); ss[nt] += __shfl_xor(ss[nt], 32);
    }
    if (quad == 0) {
#pragma unroll
        for (int nt = 0; nt < 4; ++nt) {
            sRed[((wave * 4 + nt) * 16 + m16) * 2 + 0] = s[nt];
            sRed[((wave * 4 + nt) * 16 + m16) * 2 + 1] = ss[nt];
        }
    }
    __syncthreads();
    if (tid < 64) {
        int nt = tid >> 4, c = tid & 15;
        float a = 0.f, b = 0.f;
#pragma unroll
        for (int w = 0; w < 4; ++w) {
            a += sRed[((w * 4 + nt) * 16 + c) * 2 + 0];
            b += sRed[((w * 4 + nt) * 16 + c) * 2 + 1];
        }
        atomicAdd(&stats[n0 + tid], a);
        atomicAdd(&stats[NCOL + n0 + tid], b);
    }
}

// ---------------- pass 2: BN normalize + ReLU + per-head 1x1 conv ----------------
__global__ void head_kernel(const unsigned short* __restrict__ hbuf,
                            const float* __restrict__ stats,
                            const float* __restrict__ gamma, const float* __restrict__ beta,
                            const float* __restrict__ W1_0, const float* __restrict__ W1_1,
                            const float* __restrict__ W1_2, const float* __restrict__ W1_3,
                            const float* __restrict__ W1_4,
                            const float* __restrict__ b1_0, const float* __restrict__ b1_1,
                            const float* __restrict__ b1_2, const float* __restrict__ b1_3,
                            const float* __restrict__ b1_4,
                            float* __restrict__ out) {
    __shared__ float sScale[NCOL], sShift[NCOL], sW1[NCOL * 3], sB1[16];
    int tid = threadIdx.x;
    for (int c = tid; c < NCOL; c += 256) {
        float mean = stats[c] * (1.f / (float)NVOX);
        float var = stats[NCOL + c] * (1.f / (float)NVOX) - mean * mean;
        float inv = rsqrtf(var + 1e-5f);
        float sc = inv * gamma[c];
        sScale[c] = sc;
        sShift[c] = beta[c] - mean * sc;
    }
    // W1 padded to 3 cols per head; sW1[(h*64+cc)*3 + jj]
    {
        for (int i = tid; i < 192; i += 256) { int cc = i / 3, jj = i - cc * 3; sW1[0 * 192 + i] = W1_0[cc * 3 + jj]; }
        for (int i = tid; i < 192; i += 256) { int cc = i / 3, jj = i - cc * 3; sW1[1 * 192 + i] = (jj < 2) ? W1_1[cc * 2 + jj] : 0.f; }
        for (int i = tid; i < 192; i += 256) { int cc = i / 3, jj = i - cc * 3; sW1[2 * 192 + i] = (jj < 1) ? W1_2[cc] : 0.f; }
        for (int i = tid; i < 192; i += 256) { int cc = i / 3, jj = i - cc * 3; sW1[3 * 192 + i] = W1_3[cc * 3 + jj]; }
        for (int i = tid; i < 192; i += 256) { int cc = i / 3, jj = i - cc * 3; sW1[4 * 192 + i] = (jj < 2) ? W1_4[cc * 2 + jj] : 0.f; }
    }
    if (tid == 0) {
        sB1[0] = b1_0[0]; sB1[1] = b1_0[1]; sB1[2] = b1_0[2];
        sB1[3] = b1_1[0]; sB1[4] = b1_1[1]; sB1[5] = 0.f;
        sB1[6] = b1_2[0]; sB1[7] = 0.f;    sB1[8] = 0.f;
        sB1[9] = b1_3[0]; sB1[10] = b1_3[1]; sB1[11] = b1_3[2];
        sB1[12] = b1_4[0]; sB1[13] = b1_4[1]; sB1[14] = 0.f;
    }
    __syncthreads();
    int n = blockIdx.x * 256 + tid;
    if (n >= NVOX) return;
    float acc[15];
#pragma unroll
    for (int i = 0; i < 15; ++i) acc[i] = sB1[i];
    const unsigned short* hp = hbuf + n;
#pragma unroll
    for (int h = 0; h < 5; ++h) {
#pragma unroll 8
        for (int cc = 0; cc < 64; ++cc) {
            int c = h * 64 + cc;
            unsigned raw = hp[(size_t)c * SROW];
            float v = __builtin_bit_cast(float, raw << 16);
            v = fmaxf(v * sScale[c] + sShift[c], 0.f);
            acc[h * 3 + 0] += v * sW1[c * 3 + 0];
            acc[h * 3 + 1] += v * sW1[c * 3 + 1];
            acc[h * 3 + 2] += v * sW1[c * 3 + 2];
        }
    }
    out[n * 3 + 0] = acc[0]; out[n * 3 + 1] = acc[1]; out[n * 3 + 2] = acc[2];
    out[450000 + n * 2 + 0] = acc[3]; out[450000 + n * 2 + 1] = acc[4];
    out[750000 + n] = acc[6];
    out[900000 + n * 3 + 0] = acc[9]; out[900000 + n * 3 + 1] = acc[10]; out[900000 + n * 3 + 2] = acc[11];
    out[1350000 + n * 2 + 0] = acc[12]; out[1350000 + n * 2 + 1] = acc[13];
}

extern "C" void kernel_launch(void* const* d_in, const int* in_sizes, int n_in,
                              void* d_out, int out_size, void* d_ws, size_t ws_size,
                              hipStream_t stream) {
    const float* features = (const float*)d_in[0];
    const int* nbr        = (const int*)d_in[1];
    const float* w3       = (const float*)d_in[2];
    const float* gamma    = (const float*)d_in[3];
    const float* beta     = (const float*)d_in[4];
    const float* W1_0 = (const float*)d_in[5];  const float* b1_0 = (const float*)d_in[6];
    const float* W1_1 = (const float*)d_in[7];  const float* b1_1 = (const float*)d_in[8];
    const float* W1_2 = (const float*)d_in[9];  const float* b1_2 = (const float*)d_in[10];
    const float* W1_3 = (const float*)d_in[11]; const float* b1_3 = (const float*)d_in[12];
    const float* W1_4 = (const float*)d_in[13]; const float* b1_4 = (const float*)d_in[14];
    float* out = (float*)d_out;

    char* ws = (char*)d_ws;
    unsigned short* featB = (unsigned short*)ws;               // (150000+1)*64 bf16 = 19,200,128 B
    unsigned short* Bt    = (unsigned short*)(ws + 19200128);  // 5*64*576 bf16 = 368,640 B
    float* stats          = (float*)(ws + 19568768);           // 640 f32 = 2,560 B
    unsigned short* hbuf  = (unsigned short*)(ws + 19571328);  // 320*150016 bf16 = 96,010,240 B

    prep_feat<<<(NVOX * 64 + 64 + 255) / 256, 256, 0, stream>>>(features, featB);
    prep_w3<<<184320 / 256, 256, 0, stream>>>(w3, Bt, stats);
    gemm_kernel<<<8 * 5 * 74, 256, 0, stream>>>(featB, Bt, nbr, hbuf, stats);
    head_kernel<<<(NVOX + 255) / 256, 256, 0, stream>>>(hbuf, stats, gamma, beta,
        W1_0, W1_1, W1_2, W1_3, W1_4, b1_0, b1_1, b1_2, b1_3, b1_4, out);
}

// Round 2
// 410.562 us; speedup vs baseline: 1.1624x; 1.1624x over previous
//
#include <hip/hip_runtime.h>

#define NVOX 150000
#define MTILES 586          // ceil(150000/256)
#define SROW 150016         // 586*256, column stride of h buffer
#define NCOL 320

typedef __attribute__((ext_vector_type(8))) short bf16x8;
typedef __attribute__((ext_vector_type(4))) float f32x4;

__device__ __forceinline__ unsigned short f2bf(float f) {
    unsigned u = __builtin_bit_cast(unsigned, f);
    u += 0x7fffu + ((u >> 16) & 1u);
    return (unsigned short)(u >> 16);
}

// ---------------- prep: features f32 -> bf16 (+ zero row at NVOX) ----------------
__global__ void prep_feat(const float* __restrict__ src, unsigned short* __restrict__ dst) {
    int i = blockIdx.x * 256 + threadIdx.x;
    if (i < NVOX * 64) dst[i] = f2bf(src[i]);
    else if (i < NVOX * 64 + 64) dst[i] = 0;  // zero row for invalid/pad gathers
}

// ---------------- prep: W3[h][kk][c][o] f32 -> Bt[h][o][k=kk*64+c] bf16; zero stats ----
__global__ void prep_w3(const float* __restrict__ w3, unsigned short* __restrict__ bt,
                        float* __restrict__ stats) {
    int i = blockIdx.x * 256 + threadIdx.x;   // grid is exactly 184320 threads
    int h = i / 36864;
    int rem = i - h * 36864;
    int kk = rem >> 12;
    int c = (rem >> 6) & 63;
    int o = rem & 63;
    bt[(size_t)(h * 64 + o) * 576 + kk * 64 + c] = f2bf(w3[i]);
    if (i < 2 * NCOL) stats[i] = 0.f;
}

// ---------------- gather-GEMM, direct-from-global fragments, no K-loop barriers ------
// BM=256, BN=64 (one head), 4 waves, wave tile 64x64, 16x16x32 bf16 MFMA.
// A-fragment: lane (m16,quad) of wave needs 16B of row (wave*64+mt*16+m16) at byte
// offset ks*64+quad*16 -> the 4 quads cover one full 64B line, no over-fetch.
// Row indices are owned lane<->row within the wave; shared via __shfl.
__global__ __launch_bounds__(256, 2)
void gemm_kernel(const unsigned short* __restrict__ featB,
                 const unsigned short* __restrict__ Bt,
                 const int* __restrict__ nbr,
                 unsigned short* __restrict__ hbuf,
                 float* __restrict__ stats) {
    __shared__ __align__(16) unsigned short sOut[64 * 264];  // 256 rows + 8 pad per col
    __shared__ float sRed[512];

    // XCD swizzle: 5 sibling N-tiles (heads) of one M-tile share bid%8 -> same XCD
    int bid = blockIdx.x;
    int r = bid & 7, q_ = bid >> 3;
    int ntile = q_ % 5;
    int mtile = (q_ / 5) * 8 + r;
    if (mtile >= MTILES) return;
    int m0 = mtile * 256;
    int n0 = ntile * 64;

    int tid = threadIdx.x;
    int wave = tid >> 6, lane = tid & 63;
    int quad = lane >> 4, m16 = lane & 15;

    f32x4 acc[4][4];
#pragma unroll
    for (int mt = 0; mt < 4; ++mt)
#pragma unroll
        for (int nt = 0; nt < 4; ++nt)
            acc[mt][nt] = (f32x4){0.f, 0.f, 0.f, 0.f};

    // each lane owns the neighbor list of its own row (m0 + tid)
    int my_row = m0 + tid;
    bool rowvalid = (my_row < NVOX);
    const int* np = nbr + (size_t)(rowvalid ? my_row : 0) * 9;
    int own_srow[9];
#pragma unroll
    for (int k = 0; k < 9; ++k) {
        int idx = rowvalid ? np[k] : -1;
        own_srow[k] = (idx < 0) ? NVOX : idx;   // NVOX = zero row
    }

    // per-nt B row base (row = n0 + nt*16 + m16, constant over kk)
    const unsigned short* bbase[4];
#pragma unroll
    for (int nt = 0; nt < 4; ++nt)
        bbase[nt] = Bt + (size_t)(n0 + nt * 16 + m16) * 576 + quad * 8;

    bf16x8 regA[2][4][2];   // [buf][mt][ks]
    bf16x8 regB[2][4][2];   // [buf][nt][ks]

#define STAGE(kk, buf)                                                          \
    do {                                                                        \
        _Pragma("unroll")                                                       \
        for (int mt = 0; mt < 4; ++mt) {                                        \
            int srow = __shfl(own_srow[kk], mt * 16 + m16);                     \
            const unsigned short* ap = featB + (size_t)srow * 64 + quad * 8;    \
            regA[buf][mt][0] = *(const bf16x8*)(ap);                            \
            regA[buf][mt][1] = *(const bf16x8*)(ap + 32);                       \
        }                                                                       \
        _Pragma("unroll")                                                       \
        for (int nt = 0; nt < 4; ++nt) {                                        \
            const unsigned short* bp = bbase[nt] + (kk) * 64;                   \
            regB[buf][nt][0] = *(const bf16x8*)(bp);                            \
            regB[buf][nt][1] = *(const bf16x8*)(bp + 32);                       \
        }                                                                       \
    } while (0)

    STAGE(0, 0);
#pragma unroll
    for (int kk = 0; kk < 9; ++kk) {
        int cur = kk & 1, nxt = cur ^ 1;
        if (kk < 8) STAGE(kk + 1, nxt);   // prefetch overlaps the MFMAs below
#pragma unroll
        for (int ks = 0; ks < 2; ++ks)
#pragma unroll
            for (int mt = 0; mt < 4; ++mt)
#pragma unroll
                for (int nt = 0; nt < 4; ++nt)
                    acc[mt][nt] = __builtin_amdgcn_mfma_f32_16x16x32_bf16(
                        regA[cur][mt][ks], regB[cur][nt][ks], acc[mt][nt], 0, 0, 0);
    }
#undef STAGE

    // ---- epilogue 1: reassemble tile in LDS, then fully-coalesced 512B column runs ----
#pragma unroll
    for (int mt = 0; mt < 4; ++mt) {
#pragma unroll
        for (int nt = 0; nt < 4; ++nt) {
            int col = nt * 16 + m16;
            int row = wave * 64 + mt * 16 + quad * 4;
            f32x4 v = acc[mt][nt];
            unsigned lo = (unsigned)f2bf(v.x) | ((unsigned)f2bf(v.y) << 16);
            unsigned hi = (unsigned)f2bf(v.z) | ((unsigned)f2bf(v.w) << 16);
            uint2 pk; pk.x = lo; pk.y = hi;
            *(uint2*)(sOut + col * 264 + row) = pk;
        }
    }
    __syncthreads();
#pragma unroll
    for (int i = 0; i < 8; ++i) {
        int col = i * 8 + (tid >> 5);
        int l32 = tid & 31;
        uint4 v = *(const uint4*)(sOut + col * 264 + l32 * 8);
        *(uint4*)(hbuf + (size_t)(n0 + col) * SROW + m0 + l32 * 8) = v;  // 32 lanes x 16B = 512B contiguous
    }

    // ---- epilogue 2: BN statistics (pad rows are exactly zero -> no guard) ----
    float s[4], ss[4];
#pragma unroll
    for (int nt = 0; nt < 4; ++nt) {
        float a = 0.f, b = 0.f;
#pragma unroll
        for (int mt = 0; mt < 4; ++mt) {
            f32x4 v = acc[mt][nt];
            a += v.x + v.y + v.z + v.w;
            b += v.x * v.x + v.y * v.y + v.z * v.z + v.w * v.w;
        }
        s[nt] = a; ss[nt] = b;
    }
#pragma unroll
    for (int nt = 0; nt < 4; ++nt) {
        s[nt] += __shfl_xor(s[nt], 16); s[nt] += __shfl_xor(s[nt], 32);
        ss[nt] += __shfl_xor(ss[nt], 16); ss[nt] += __shfl_xor(ss[nt], 32);
    }
    if (quad == 0) {
#pragma unroll
        for (int nt = 0; nt < 4; ++nt) {
            sRed[((wave * 4 + nt) * 16 + m16) * 2 + 0] = s[nt];
            sRed[((wave * 4 + nt) * 16 + m16) * 2 + 1] = ss[nt];
        }
    }
    __syncthreads();
    if (tid < 64) {
        int nt = tid >> 4, c = tid & 15;
        float a = 0.f, b = 0.f;
#pragma unroll
        for (int w = 0; w < 4; ++w) {
            a += sRed[((w * 4 + nt) * 16 + c) * 2 + 0];
            b += sRed[((w * 4 + nt) * 16 + c) * 2 + 1];
        }
        atomicAdd(&stats[n0 + tid], a);
        atomicAdd(&stats[NCOL + n0 + tid], b);
    }
}

// ---------------- pass 2: BN normalize + ReLU + per-head 1x1 conv (2 rows/thread) ----
__global__ void head_kernel(const unsigned short* __restrict__ hbuf,
                            const float* __restrict__ stats,
                            const float* __restrict__ gamma, const float* __restrict__ beta,
                            const float* __restrict__ W1_0, const float* __restrict__ W1_1,
                            const float* __restrict__ W1_2, const float* __restrict__ W1_3,
                            const float* __restrict__ W1_4,
                            const float* __restrict__ b1_0, const float* __restrict__ b1_1,
                            const float* __restrict__ b1_2, const float* __restrict__ b1_3,
                            const float* __restrict__ b1_4,
                            float* __restrict__ out) {
    __shared__ float sScale[NCOL], sShift[NCOL], sW1[NCOL * 3], sB1[16];
    int tid = threadIdx.x;
    for (int c = tid; c < NCOL; c += 128) {
        float mean = stats[c] * (1.f / (float)NVOX);
        float var = stats[NCOL + c] * (1.f / (float)NVOX) - mean * mean;
        float inv = rsqrtf(var + 1e-5f);
        float sc = inv * gamma[c];
        sScale[c] = sc;
        sShift[c] = beta[c] - mean * sc;
    }
    for (int i = tid; i < 192; i += 128) { int cc = i / 3, jj = i - cc * 3; sW1[0 * 192 + i] = W1_0[cc * 3 + jj]; }
    for (int i = tid; i < 192; i += 128) { int cc = i / 3, jj = i - cc * 3; sW1[1 * 192 + i] = (jj < 2) ? W1_1[cc * 2 + jj] : 0.f; }
    for (int i = tid; i < 192; i += 128) { int cc = i / 3, jj = i - cc * 3; sW1[2 * 192 + i] = (jj < 1) ? W1_2[cc] : 0.f; }
    for (int i = tid; i < 192; i += 128) { int cc = i / 3, jj = i - cc * 3; sW1[3 * 192 + i] = W1_3[cc * 3 + jj]; }
    for (int i = tid; i < 192; i += 128) { int cc = i / 3, jj = i - cc * 3; sW1[4 * 192 + i] = (jj < 2) ? W1_4[cc * 2 + jj] : 0.f; }
    if (tid == 0) {
        sB1[0] = b1_0[0]; sB1[1] = b1_0[1]; sB1[2] = b1_0[2];
        sB1[3] = b1_1[0]; sB1[4] = b1_1[1]; sB1[5] = 0.f;
        sB1[6] = b1_2[0]; sB1[7] = 0.f;    sB1[8] = 0.f;
        sB1[9] = b1_3[0]; sB1[10] = b1_3[1]; sB1[11] = b1_3[2];
        sB1[12] = b1_4[0]; sB1[13] = b1_4[1]; sB1[14] = 0.f;
    }
    __syncthreads();
    int t = blockIdx.x * 128 + tid;
    int n = 2 * t;                       // rows n, n+1
    if (n >= NVOX) return;
    float acc0[15], acc1[15];
#pragma unroll
    for (int i = 0; i < 15; ++i) { acc0[i] = sB1[i]; acc1[i] = sB1[i]; }
    const unsigned short* hp = hbuf + n;
#pragma unroll 4
    for (int c = 0; c < NCOL; ++c) {
        unsigned raw = *(const unsigned*)(hp + (size_t)c * SROW);
        float v0 = __builtin_bit_cast(float, raw << 16);
        float v1 = __builtin_bit_cast(float, raw & 0xffff0000u);
        float sc = sScale[c], sh = sShift[c];
        v0 = fmaxf(v0 * sc + sh, 0.f);
        v1 = fmaxf(v1 * sc + sh, 0.f);
        int h3 = (c >> 6) * 3;
        const float* w = &sW1[c * 3];
        acc0[h3 + 0] += v0 * w[0]; acc0[h3 + 1] += v0 * w[1]; acc0[h3 + 2] += v0 * w[2];
        acc1[h3 + 0] += v1 * w[0]; acc1[h3 + 1] += v1 * w[1]; acc1[h3 + 2] += v1 * w[2];
    }
    out[n * 3 + 0] = acc0[0]; out[n * 3 + 1] = acc0[1]; out[n * 3 + 2] = acc0[2];
    out[(n + 1) * 3 + 0] = acc1[0]; out[(n + 1) * 3 + 1] = acc1[1]; out[(n + 1) * 3 + 2] = acc1[2];
    out[450000 + n * 2 + 0] = acc0[3]; out[450000 + n * 2 + 1] = acc0[4];
    out[450000 + (n + 1) * 2 + 0] = acc1[3]; out[450000 + (n + 1) * 2 + 1] = acc1[4];
    out[750000 + n] = acc0[6]; out[750000 + n + 1] = acc1[6];
    out[900000 + n * 3 + 0] = acc0[9]; out[900000 + n * 3 + 1] = acc0[10]; out[900000 + n * 3 + 2] = acc0[11];
    out[900000 + (n + 1) * 3 + 0] = acc1[9]; out[900000 + (n + 1) * 3 + 1] = acc1[10]; out[900000 + (n + 1) * 3 + 2] = acc1[11];
    out[1350000 + n * 2 + 0] = acc0[12]; out[1350000 + n * 2 + 1] = acc0[13];
    out[1350000 + (n + 1) * 2 + 0] = acc1[12]; out[1350000 + (n + 1) * 2 + 1] = acc1[13];
}

extern "C" void kernel_launch(void* const* d_in, const int* in_sizes, int n_in,
                              void* d_out, int out_size, void* d_ws, size_t ws_size,
                              hipStream_t stream) {
    const float* features = (const float*)d_in[0];
    const int* nbr        = (const int*)d_in[1];
    const float* w3       = (const float*)d_in[2];
    const float* gamma    = (const float*)d_in[3];
    const float* beta     = (const float*)d_in[4];
    const float* W1_0 = (const float*)d_in[5];  const float* b1_0 = (const float*)d_in[6];
    const float* W1_1 = (const float*)d_in[7];  const float* b1_1 = (const float*)d_in[8];
    const float* W1_2 = (const float*)d_in[9];  const float* b1_2 = (const float*)d_in[10];
    const float* W1_3 = (const float*)d_in[11]; const float* b1_3 = (const float*)d_in[12];
    const float* W1_4 = (const float*)d_in[13]; const float* b1_4 = (const float*)d_in[14];
    float* out = (float*)d_out;

    char* ws = (char*)d_ws;
    unsigned short* featB = (unsigned short*)ws;               // (150000+1)*64 bf16
    unsigned short* Bt    = (unsigned short*)(ws + 19200128);  // 5*64*576 bf16
    float* stats          = (float*)(ws + 19568768);           // 640 f32
    unsigned short* hbuf  = (unsigned short*)(ws + 19571328);  // 320*150016 bf16

    prep_feat<<<(NVOX * 64 + 64 + 255) / 256, 256, 0, stream>>>(features, featB);
    prep_w3<<<184320 / 256, 256, 0, stream>>>(w3, Bt, stats);
    gemm_kernel<<<8 * 5 * 74, 256, 0, stream>>>(featB, Bt, nbr, hbuf, stats);
    head_kernel<<<(NVOX / 2 + 127) / 128, 128, 0, stream>>>(hbuf, stats, gamma, beta,
        W1_0, W1_1, W1_2, W1_3, W1_4, b1_0, b1_1, b1_2, b1_3, b1_4, out);
}

// Round 3
// 230.557 us; speedup vs baseline: 2.0699x; 1.7807x over previous
//
#include <hip/hip_runtime.h>

#define NVOX 150000
#define BM 128
#define MTILES 1172         // ceil(150000/128)
#define SROW 150016         // 1172*128, column stride of h buffer
#define NCOL 320

typedef __attribute__((ext_vector_type(8))) short bf16x8;
typedef __attribute__((ext_vector_type(4))) float f32x4;

__device__ __forceinline__ unsigned short f2bf(float f) {
    unsigned u = __builtin_bit_cast(unsigned, f);
    u += 0x7fffu + ((u >> 16) & 1u);
    return (unsigned short)(u >> 16);
}

__device__ __forceinline__ void gld16(const void* g, void* l) {
    __builtin_amdgcn_global_load_lds(
        (const __attribute__((address_space(1))) unsigned int*)g,
        (__attribute__((address_space(3))) unsigned int*)l, 16, 0, 0);
}

// ---------------- prep: features f32 -> bf16 (+ zero row at NVOX) ----------------
__global__ void prep_feat(const float* __restrict__ src, unsigned short* __restrict__ dst) {
    int i = blockIdx.x * 256 + threadIdx.x;
    if (i < NVOX * 64) dst[i] = f2bf(src[i]);
    else if (i < NVOX * 64 + 64) dst[i] = 0;  // zero row for invalid/pad gathers
}

// ---- prep: W3[h][kk][c][o] f32 -> Bt2 chunk-major bf16: [(h*9+kk)*8 + c16][o][c&7] ----
__global__ void prep_w3(const float* __restrict__ w3, unsigned short* __restrict__ bt,
                        float* __restrict__ stats) {
    int i = blockIdx.x * 256 + threadIdx.x;   // grid is exactly 184320 threads
    int h = i / 36864;
    int rem = i - h * 36864;
    int kk = rem >> 12;
    int c = (rem >> 6) & 63;
    int o = rem & 63;
    // 16B unit (8 bf16) index: ((h*9+kk)*8 + c/8)*512 + o*8 + (c%8)
    bt[(size_t)(((h * 9 + kk) * 8) + (c >> 3)) * 512 + o * 8 + (c & 7)] = f2bf(w3[i]);
    if (i < 2 * NCOL) stats[i] = 0.f;
}

// ---------------- gather-GEMM: async global_load_lds staging, chunk-major LDS ----------
// BM=128, BN=64 (one head), BK=64 (one kk), 4 waves, wave tile 64x32.
// LDS chunk-major: sA[c16][row]*16B (c16 = ks*4+quad byte-chunk of the 128B k-row).
// ds_read_b128 frag reads: 16 lanes stride 16B -> 2-way bank alias only (free).
__global__ __launch_bounds__(256, 4)
void gemm_kernel(const unsigned short* __restrict__ featB,
                 const unsigned short* __restrict__ Bt2,
                 const int* __restrict__ nbr,
                 unsigned short* __restrict__ hbuf,
                 float* __restrict__ stats) {
    __shared__ __align__(16) char smem[30208];
    constexpr int SB_OFF = 16384;    // 8 KB B stage
    constexpr int IDX_OFF = 24576;   // 9*128 int byte-offsets
    constexpr int SRED_OFF = 29184;  // 4*2*16*2 floats

    // XCD swizzle: the 5 head-blocks of one mtile share bid%8 -> same XCD (A L2 reuse)
    int bid = blockIdx.x;
    int r = bid & 7, q = bid >> 3;
    int ntile = q % 5;
    int mtile = (q / 5) * 8 + r;
    if (mtile >= MTILES) return;
    int m0 = mtile * BM;
    int n0 = ntile * 64;

    int tid = threadIdx.x;
    int w = tid >> 6, lane = tid & 63;
    int quad = lane >> 4, m16 = lane & 15;

    // ---- stage neighbor byte-offset table: sIdx[kk][row] = srow*128 ----
    for (int lin = tid; lin < BM * 9; lin += 256) {
        int row = lin / 9, kkq = lin - row * 9;
        int v = -1;
        if (m0 + row < NVOX) v = nbr[(size_t)(m0 + row) * 9 + kkq];
        *(int*)(smem + IDX_OFF + (kkq * BM + row) * 4) = ((v < 0) ? NVOX : v) * 128;
    }
    __syncthreads();

    f32x4 acc[4][2];
#pragma unroll
    for (int mt = 0; mt < 4; ++mt)
#pragma unroll
        for (int nt = 0; nt < 2; ++nt)
            acc[mt][nt] = (f32x4){0.f, 0.f, 0.f, 0.f};

    const char* fb = (const char*)featB;
    const char* bsrc = (const char*)Bt2 + (size_t)ntile * 73728;  // head base (bytes)
    char* sA = smem;
    char* sB = smem + SB_OFF;

    int mrow = (w >> 1) * 64;   // wave's row half
    int ncol = (w & 1) * 32;    // wave's col half

    for (int kk = 0; kk < 9; ++kk) {
        // per-lane gather byte offsets for rows lane and 64+lane
        int off0 = *(const int*)(smem + IDX_OFF + (kk * BM + lane) * 4);
        int off1 = *(const int*)(smem + IDX_OFF + (kk * BM + 64 + lane) * 4);
        int c16a = w * 2, c16b = w * 2 + 1;
        // A: 4 async 1KB gathers (64 rows x 16B chunk each); LDS dst wave-uniform
        gld16(fb + off0 + c16a * 16, sA + c16a * 2048);
        gld16(fb + off1 + c16a * 16, sA + c16a * 2048 + 1024);
        gld16(fb + off0 + c16b * 16, sA + c16b * 2048);
        gld16(fb + off1 + c16b * 16, sA + c16b * 2048 + 1024);
        // B: 2 async 1KB sequential copies (chunk-major source layout)
        gld16(bsrc + (kk * 8 + c16a) * 1024 + lane * 16, sB + c16a * 1024);
        gld16(bsrc + (kk * 8 + c16b) * 1024 + lane * 16, sB + c16b * 1024);
        __syncthreads();   // vmcnt(0)+barrier: stage complete block-wide
        // ---- compute: 12 ds_read_b128 + 16 MFMAs ----
        bf16x8 af[2][4], bfr[2][2];
#pragma unroll
        for (int ks = 0; ks < 2; ++ks) {
#pragma unroll
            for (int mt = 0; mt < 4; ++mt)
                af[ks][mt] = *(const bf16x8*)(sA + (ks * 4 + quad) * 2048 +
                                              (mrow + mt * 16 + m16) * 16);
#pragma unroll
            for (int nt = 0; nt < 2; ++nt)
                bfr[ks][nt] = *(const bf16x8*)(sB + (ks * 4 + quad) * 1024 +
                                               (ncol + nt * 16 + m16) * 16);
        }
#pragma unroll
        for (int ks = 0; ks < 2; ++ks)
#pragma unroll
            for (int mt = 0; mt < 4; ++mt)
#pragma unroll
                for (int nt = 0; nt < 2; ++nt)
                    acc[mt][nt] = __builtin_amdgcn_mfma_f32_16x16x32_bf16(
                        af[ks][mt], bfr[ks][nt], acc[mt][nt], 0, 0, 0);
        __syncthreads();   // compute done block-wide before restaging
    }

    // ---- epilogue 1: transpose via LDS (aliases sA/sB), coalesced column stores ----
#pragma unroll
    for (int mt = 0; mt < 4; ++mt) {
#pragma unroll
        for (int nt = 0; nt < 2; ++nt) {
            int col = ncol + nt * 16 + m16;
            int row = mrow + mt * 16 + quad * 4;
            f32x4 v = acc[mt][nt];
            unsigned lo = (unsigned)f2bf(v.x) | ((unsigned)f2bf(v.y) << 16);
            unsigned hi = (unsigned)f2bf(v.z) | ((unsigned)f2bf(v.w) << 16);
            uint2 pk; pk.x = lo; pk.y = hi;
            *(uint2*)(smem + col * 272 + row * 2) = pk;   // col stride 136 ushorts
        }
    }
    __syncthreads();
#pragma unroll
    for (int it = 0; it < 8; ++it) {
        int col = it * 8 + (tid >> 5);
        int l32 = tid & 31;
        uint2 v = *(const uint2*)(smem + col * 272 + l32 * 8);
        *(uint2*)(hbuf + (size_t)(n0 + col) * SROW + m0 + l32 * 4) = v;  // 256B runs
    }

    // ---- epilogue 2: BN statistics (pad/invalid rows are exact zeros) ----
    float s[2], ss[2];
#pragma unroll
    for (int nt = 0; nt < 2; ++nt) {
        float a = 0.f, b = 0.f;
#pragma unroll
        for (int mt = 0; mt < 4; ++mt) {
            f32x4 v = acc[mt][nt];
            a += v.x + v.y + v.z + v.w;
            b += v.x * v.x + v.y * v.y + v.z * v.z + v.w * v.w;
        }
        s[nt] = a; ss[nt] = b;
        s[nt] += __shfl_xor(s[nt], 16); s[nt] += __shfl_xor(s[nt], 32);
        ss[nt] += __shfl_xor(ss[nt], 16); ss[nt] += __shfl_xor(ss[nt], 32);
    }
    if (quad == 0) {
#pragma unroll
        for (int nt = 0; nt < 2; ++nt) {
            float* p = (float*)(smem + SRED_OFF + ((w * 2 + nt) * 16 + m16) * 8);
            p[0] = s[nt]; p[1] = ss[nt];
        }
    }
    __syncthreads();
    if (tid < 64) {
        int col = tid;
        int half = col >> 5, nt = (col >> 4) & 1, mc = col & 15;
        const float* p0 = (const float*)(smem + SRED_OFF + ((half * 2 + nt) * 16 + mc) * 8);
        const float* p1 = (const float*)(smem + SRED_OFF + (((2 + half) * 2 + nt) * 16 + mc) * 8);
        atomicAdd(&stats[n0 + col], p0[0] + p1[0]);
        atomicAdd(&stats[NCOL + n0 + col], p0[1] + p1[1]);
    }
}

// ------- pass 2: BN + ReLU + per-head 1x1 conv; ALL accumulator indexing static -------
__global__ void head_kernel(const unsigned short* __restrict__ hbuf,
                            const float* __restrict__ stats,
                            const float* __restrict__ gamma, const float* __restrict__ beta,
                            const float* __restrict__ W1_0, const float* __restrict__ W1_1,
                            const float* __restrict__ W1_2, const float* __restrict__ W1_3,
                            const float* __restrict__ W1_4,
                            const float* __restrict__ b1_0, const float* __restrict__ b1_1,
                            const float* __restrict__ b1_2, const float* __restrict__ b1_3,
                            const float* __restrict__ b1_4,
                            float* __restrict__ out) {
    __shared__ float sScale[NCOL], sShift[NCOL], sW1[NCOL * 3], sB1[16];
    int tid = threadIdx.x;
    for (int c = tid; c < NCOL; c += 256) {
        float mean = stats[c] * (1.f / (float)NVOX);
        float var = stats[NCOL + c] * (1.f / (float)NVOX) - mean * mean;
        float inv = rsqrtf(var + 1e-5f);
        float sc = inv * gamma[c];
        sScale[c] = sc;
        sShift[c] = beta[c] - mean * sc;
    }
    for (int i = tid; i < 192; i += 256) { int cc = i / 3, jj = i - cc * 3; sW1[0 * 192 + i] = W1_0[cc * 3 + jj]; }
    for (int i = tid; i < 192; i += 256) { int cc = i / 3, jj = i - cc * 3; sW1[1 * 192 + i] = (jj < 2) ? W1_1[cc * 2 + jj] : 0.f; }
    for (int i = tid; i < 192; i += 256) { int cc = i / 3, jj = i - cc * 3; sW1[2 * 192 + i] = (jj < 1) ? W1_2[cc] : 0.f; }
    for (int i = tid; i < 192; i += 256) { int cc = i / 3, jj = i - cc * 3; sW1[3 * 192 + i] = W1_3[cc * 3 + jj]; }
    for (int i = tid; i < 192; i += 256) { int cc = i / 3, jj = i - cc * 3; sW1[4 * 192 + i] = (jj < 2) ? W1_4[cc * 2 + jj] : 0.f; }
    if (tid == 0) {
        sB1[0] = b1_0[0]; sB1[1] = b1_0[1]; sB1[2] = b1_0[2];
        sB1[3] = b1_1[0]; sB1[4] = b1_1[1]; sB1[5] = 0.f;
        sB1[6] = b1_2[0]; sB1[7] = 0.f;    sB1[8] = 0.f;
        sB1[9] = b1_3[0]; sB1[10] = b1_3[1]; sB1[11] = b1_3[2];
        sB1[12] = b1_4[0]; sB1[13] = b1_4[1]; sB1[14] = 0.f;
    }
    __syncthreads();
    int n = 2 * (blockIdx.x * 256 + tid);    // rows n, n+1 (NVOX even)
    if (n >= NVOX) return;
    const unsigned short* hp = hbuf + n;
#pragma unroll
    for (int h = 0; h < 5; ++h) {
        float x0 = sB1[h * 3 + 0], x1 = sB1[h * 3 + 1], x2 = sB1[h * 3 + 2];
        float y0 = x0, y1 = x1, y2 = x2;
#pragma unroll 8
        for (int cc = 0; cc < 64; ++cc) {
            int c = h * 64 + cc;
            unsigned raw = *(const unsigned*)(hp + (size_t)c * SROW);
            float v0 = __builtin_bit_cast(float, raw << 16);
            float v1 = __builtin_bit_cast(float, raw & 0xffff0000u);
            float sc = sScale[c], sh = sShift[c];
            v0 = fmaxf(v0 * sc + sh, 0.f);
            v1 = fmaxf(v1 * sc + sh, 0.f);
            float w0 = sW1[c * 3 + 0], w1 = sW1[c * 3 + 1], w2 = sW1[c * 3 + 2];
            x0 += v0 * w0; x1 += v0 * w1; x2 += v0 * w2;
            y0 += v1 * w0; y1 += v1 * w1; y2 += v1 * w2;
        }
        if (h == 0) {
            out[n * 3 + 0] = x0; out[n * 3 + 1] = x1; out[n * 3 + 2] = x2;
            out[(n + 1) * 3 + 0] = y0; out[(n + 1) * 3 + 1] = y1; out[(n + 1) * 3 + 2] = y2;
        } else if (h == 1) {
            out[450000 + n * 2 + 0] = x0; out[450000 + n * 2 + 1] = x1;
            out[450000 + (n + 1) * 2 + 0] = y0; out[450000 + (n + 1) * 2 + 1] = y1;
        } else if (h == 2) {
            out[750000 + n] = x0; out[750000 + n + 1] = y0;
        } else if (h == 3) {
            out[900000 + n * 3 + 0] = x0; out[900000 + n * 3 + 1] = x1; out[900000 + n * 3 + 2] = x2;
            out[900000 + (n + 1) * 3 + 0] = y0; out[900000 + (n + 1) * 3 + 1] = y1; out[900000 + (n + 1) * 3 + 2] = y2;
        } else {
            out[1350000 + n * 2 + 0] = x0; out[1350000 + n * 2 + 1] = x1;
            out[1350000 + (n + 1) * 2 + 0] = y0; out[1350000 + (n + 1) * 2 + 1] = y1;
        }
    }
}

extern "C" void kernel_launch(void* const* d_in, const int* in_sizes, int n_in,
                              void* d_out, int out_size, void* d_ws, size_t ws_size,
                              hipStream_t stream) {
    const float* features = (const float*)d_in[0];
    const int* nbr        = (const int*)d_in[1];
    const float* w3       = (const float*)d_in[2];
    const float* gamma    = (const float*)d_in[3];
    const float* beta     = (const float*)d_in[4];
    const float* W1_0 = (const float*)d_in[5];  const float* b1_0 = (const float*)d_in[6];
    const float* W1_1 = (const float*)d_in[7];  const float* b1_1 = (const float*)d_in[8];
    const float* W1_2 = (const float*)d_in[9];  const float* b1_2 = (const float*)d_in[10];
    const float* W1_3 = (const float*)d_in[11]; const float* b1_3 = (const float*)d_in[12];
    const float* W1_4 = (const float*)d_in[13]; const float* b1_4 = (const float*)d_in[14];
    float* out = (float*)d_out;

    char* ws = (char*)d_ws;
    unsigned short* featB = (unsigned short*)ws;               // (150000+1)*64 bf16
    unsigned short* Bt2   = (unsigned short*)(ws + 19200128);  // 5*9*8*512 bf16
    float* stats          = (float*)(ws + 19568768);           // 640 f32
    unsigned short* hbuf  = (unsigned short*)(ws + 19571328);  // 320*150016 bf16

    prep_feat<<<(NVOX * 64 + 64 + 255) / 256, 256, 0, stream>>>(features, featB);
    prep_w3<<<184320 / 256, 256, 0, stream>>>(w3, Bt2, stats);
    gemm_kernel<<<8 * 5 * 147, 256, 0, stream>>>(featB, Bt2, nbr, hbuf, stats);
    head_kernel<<<(NVOX / 2 + 255) / 256, 256, 0, stream>>>(hbuf, stats, gamma, beta,
        W1_0, W1_1, W1_2, W1_3, W1_4, b1_0, b1_1, b1_2, b1_3, b1_4, out);
}